// Round 5
// baseline (472.744 us; speedup 1.0000x reference)
//
#include <hip/hip_runtime.h>
#include <math.h>

#define EPSV   1e-5f
#define SLOPE  0.2f

#define B_   2
#define N_   2048
#define M_   64
#define C_   128
#define C2_  256
#define H_   128
#define O_   64

typedef short  s16x8 __attribute__((ext_vector_type(8)));
typedef ushort u16x8 __attribute__((ext_vector_type(8)));
typedef float  f32x4 __attribute__((ext_vector_type(4)));

// ---------------- workspace (float offsets) ----------------
#define WS_H1      0            // [4096*128]
#define WS_HC      524288       // [128*128]
#define WS_PMAX    540672       // [4096*256]
#define WS_PMIN    1589248      // [4096*256]
#define WS_W2BF    2637824      // 256*128 bf16
#define WS_W3BF    2654208      // 256*256 bf16
#define WS_SUMA    2686976      // [2*128]
#define WS_SSQA    2687232
#define WS_SUMC    2687488
#define WS_SSQC    2687744
#define WS_SUM2    2688000      // [256]
#define WS_SSQ2    2688256
#define WS_SUM3    2688512
#define WS_SSQ3    2688768
#define WS_SUM4    2689024      // [128]
#define WS_SSQ4    2689152
#define WS_SUM5    2689280      // [64]
#define WS_SSQ5    2689344
#define WS_ZERO_BEG WS_SUMA
#define WS_ZERO_CNT (2689408 - WS_SUMA)
#define WS_SC1     2689408
#define WS_SH1     2689536
#define WS_SC2     2689664
#define WS_SH2     2689920
#define WS_SC3     2690176
#define WS_SH3     2690432
#define WS_SC4     2690688
#define WS_SH4     2690816
#define WS_SC5     2690944
#define WS_SH5     2691008
#define WS_X4      WS_H1        // reuse (H1 dead after k_x3f)
#define WS_X5      WS_PMIN      // reuse (PMIN dead after k_fc1)

__device__ inline ushort f2b(float x) {
  unsigned u = __builtin_bit_cast(unsigned, x);
  u += 0x7fffu + ((u >> 16) & 1u);
  return (ushort)(u >> 16);
}
__device__ inline float lrelu(float x) { return fmaxf(x, SLOPE * x); }

// ---------------- W -> bf16 ----------------
__global__ __launch_bounds__(256) void k_cvtW(const float* __restrict__ W2,
                                              const float* __restrict__ W3,
                                              ushort* __restrict__ w2b,
                                              ushort* __restrict__ w3b) {
  int i = blockIdx.x * 256 + threadIdx.x;
  if (i < C2_ * C_) w2b[i] = f2b(W2[i]);
  w3b[i] = f2b(W3[i]);
}

// ---------------- projections, 4 rows/block ----------------
__global__ __launch_bounds__(128) void k_proj4(const float* __restrict__ x,
                                               const float* __restrict__ W1,
                                               float* __restrict__ out, int col_off) {
  __shared__ float xs[4][C_];
  int row0 = blockIdx.x * 4, t = threadIdx.x;
#pragma unroll
  for (int r = 0; r < 4; ++r) xs[r][t] = x[(row0 + r) * C_ + t];
  __syncthreads();
  const float* w = W1 + t * (2 * C_) + col_off;
  float acc[4] = {0.f, 0.f, 0.f, 0.f};
  for (int c = 0; c < C_; c += 4) {
    float4 wv = *(const float4*)(w + c);
#pragma unroll
    for (int r = 0; r < 4; ++r) {
      float4 xv = *(const float4*)(&xs[r][c]);
      acc[r] = fmaf(wv.x, xv.x, fmaf(wv.y, xv.y, fmaf(wv.z, xv.z, fmaf(wv.w, xv.w, acc[r]))));
    }
  }
#pragma unroll
  for (int r = 0; r < 4; ++r) out[(row0 + r) * C_ + t] = acc[r];
}

// ---------------- coalesced per-(b,c) row stats ----------------
__global__ __launch_bounds__(256) void k_rowstats(const float* __restrict__ x,
                                                  float* __restrict__ sums,
                                                  float* __restrict__ ssqs,
                                                  int rows_per_b) {
  __shared__ float red[256];
  int t = threadIdx.x, c = t & 127, rr = t >> 7;
  int r0 = blockIdx.x * 32, b = r0 / rows_per_b;
  float s = 0.f, s2 = 0.f;
  for (int i = 0; i < 16; ++i) {
    float v = x[(r0 + rr + i * 2) * C_ + c];
    s += v; s2 = fmaf(v, v, s2);
  }
  red[t] = s;
  __syncthreads();
  if (t < 128) atomicAdd(&sums[b * C_ + t], red[t] + red[t + 128]);
  __syncthreads();
  red[t] = s2;
  __syncthreads();
  if (t < 128) atomicAdd(&ssqs[b * C_ + t], red[t] + red[t + 128]);
}

// ---------------- analytic BN1 params ----------------
__global__ __launch_bounds__(128) void k_fin1(const float* __restrict__ sumA,
                                              const float* __restrict__ ssqA,
                                              const float* __restrict__ sumC,
                                              const float* __restrict__ ssqC,
                                              const float* __restrict__ g,
                                              const float* __restrict__ bt,
                                              float* __restrict__ scale,
                                              float* __restrict__ shift) {
  int c = threadIdx.x;
  float sA0 = sumA[c], sA1 = sumA[C_ + c];
  float qA0 = ssqA[c], qA1 = ssqA[C_ + c];
  float sC0 = sumC[c], sC1 = sumC[C_ + c];
  float qC0 = ssqC[c], qC1 = ssqC[C_ + c];
  const float cnt = (float)B_ * N_ * M_;
  float mean = ((float)M_ * (sA0 + sA1) + (float)N_ * (sC0 + sC1)) / cnt;
  float ex2 = ((float)M_ * (qA0 + qA1) + (float)N_ * (qC0 + qC1)
               + 2.f * (sA0 * sC0 + sA1 * sC1)) / cnt;
  float var = ex2 - mean * mean;
  float sc = g[c] * rsqrtf(var + EPSV);
  scale[c] = sc;
  shift[c] = bt[c] - mean * sc;
}

// ---------------- finalize BN params from sums ----------------
__global__ void k_finalize(const float* __restrict__ sum, const float* __restrict__ ssq,
                           const float* __restrict__ g, const float* __restrict__ bt,
                           float* __restrict__ scale, float* __restrict__ shift,
                           int nch, float inv_cnt) {
  int o = threadIdx.x + blockIdx.x * blockDim.x;
  if (o < nch) {
    float mean = sum[o] * inv_cnt;
    float var = ssq[o] * inv_cnt - mean * mean;
    float sc = g[o] * rsqrtf(var + EPSV);
    scale[o] = sc;
    shift[o] = bt[o] - mean * sc;
  }
}

// ---------------- build S1 tile: 256 rows (4 n x 64 m), bf16 swizzled ----------------
// S1 ushort idx: r*128 + ((j ^ (r&7))<<3) + (c&7),  j = c>>3
__device__ inline void build_S1_256(ushort* S1, const float* __restrict__ h1,
                                    const float* __restrict__ hc,
                                    const float* __restrict__ sc1g,
                                    const float* __restrict__ sh1g,
                                    int nf0, int b,
                                    float (*h1s)[C_], float* sc1, float* sh1) {
  int t = threadIdx.x;
  h1s[t >> 7][t & 127] = h1[(nf0 + (t >> 7)) * C_ + (t & 127)];
  if (t < C_) { sc1[t] = sc1g[t]; sh1[t] = sh1g[t]; }
  __syncthreads();
  const float* hcb = hc + b * M_ * C_;
#pragma unroll
  for (int i = 0; i < 8; ++i) {
    int s = t + i * 512;
    int r = s >> 4, j = s & 15, c0 = j << 3;
    const float* hr = h1s[r >> 6];
    const float* src = hcb + (r & 63) * C_ + c0;
    float4 v0 = *(const float4*)(src);
    float4 v1 = *(const float4*)(src + 4);
    u16x8 q;
    q[0] = f2b(lrelu(fmaf(sc1[c0+0], hr[c0+0] + v0.x, sh1[c0+0])));
    q[1] = f2b(lrelu(fmaf(sc1[c0+1], hr[c0+1] + v0.y, sh1[c0+1])));
    q[2] = f2b(lrelu(fmaf(sc1[c0+2], hr[c0+2] + v0.z, sh1[c0+2])));
    q[3] = f2b(lrelu(fmaf(sc1[c0+3], hr[c0+3] + v0.w, sh1[c0+3])));
    q[4] = f2b(lrelu(fmaf(sc1[c0+4], hr[c0+4] + v1.x, sh1[c0+4])));
    q[5] = f2b(lrelu(fmaf(sc1[c0+5], hr[c0+5] + v1.y, sh1[c0+5])));
    q[6] = f2b(lrelu(fmaf(sc1[c0+6], hr[c0+6] + v1.z, sh1[c0+6])));
    q[7] = f2b(lrelu(fmaf(sc1[c0+7], hr[c0+7] + v1.w, sh1[c0+7])));
    *(u16x8*)(S1 + r * C_ + ((j ^ (r & 7)) << 3)) = q;
  }
  __syncthreads();
}

// ---------------- pass B: stats of X2 over a 256-row tile ----------------
__global__ __launch_bounds__(512, 2) void k_x2f(const float* __restrict__ h1,
                                                const float* __restrict__ hc,
                                                const float* __restrict__ sc1g,
                                                const float* __restrict__ sh1g,
                                                const ushort* __restrict__ W2b,
                                                float* __restrict__ sum2,
                                                float* __restrict__ ssq2) {
  __shared__ __align__(16) ushort S1[256 * C_];   // 64 KB
  __shared__ float h1s[4][C_], sc1[C_], sh1[C_];
  int nf0 = blockIdx.x * 4, b = nf0 >> 11;
  build_S1_256(S1, h1, hc, sc1g, sh1g, nf0, b, h1s, sc1, sh1);
  int t = threadIdx.x, wv = t >> 6, lane = t & 63, lr = lane & 15, lg = lane >> 4;
  int RB = (wv >> 2) * 128, OB = (wv & 3) * 64;

  s16x8 b2[4][4];
  const ushort* w2base = W2b + (OB + lr) * C_ + lg * 8;
#pragma unroll
  for (int ot = 0; ot < 4; ++ot)
#pragma unroll
    for (int ks = 0; ks < 4; ++ks)
      b2[ot][ks] = *(const s16x8*)(w2base + ot * 16 * C_ + ks * 32);

  float sm[4] = {0.f, 0.f, 0.f, 0.f}, sq[4] = {0.f, 0.f, 0.f, 0.f};
#pragma unroll
  for (int mt = 0; mt < 8; ++mt) {
    int rowm = RB + mt * 16 + lr, rx = rowm & 7;
    const ushort* s1r = S1 + rowm * C_;
    s16x8 a[4];
#pragma unroll
    for (int ks = 0; ks < 4; ++ks)
      a[ks] = *(const s16x8*)(s1r + (((ks * 4 + lg) ^ rx) << 3));
#pragma unroll
    for (int ot = 0; ot < 4; ++ot) {
      f32x4 acc = {0.f, 0.f, 0.f, 0.f};
#pragma unroll
      for (int ks = 0; ks < 4; ++ks)
        acc = __builtin_amdgcn_mfma_f32_16x16x32_bf16(a[ks], b2[ot][ks], acc, 0, 0, 0);
#pragma unroll
      for (int r = 0; r < 4; ++r) {
        sm[ot] += acc[r];
        sq[ot] = fmaf(acc[r], acc[r], sq[ot]);
      }
    }
  }
#pragma unroll
  for (int ot = 0; ot < 4; ++ot) {
    sm[ot] += __shfl_xor(sm[ot], 16); sm[ot] += __shfl_xor(sm[ot], 32);
    sq[ot] += __shfl_xor(sq[ot], 16); sq[ot] += __shfl_xor(sq[ot], 32);
    if (lg == 0) {
      int o = OB + ot * 16 + lr;
      atomicAdd(&sum2[o], sm[ot]);
      atomicAdd(&ssq2[o], sq[ot]);
    }
  }
}

// ---------------- pass C: stage2 + stage3 + pool, per-half (spill-free) ----------------
// LDS: S1 (64 KB, live whole kernel) + S2 (64 KB, holds one 128-row half).
// S2 ushort idx: ml*256 + ((j ^ (ml&7))<<3) + (c&7), j = c>>3 (bank-correct swizzle)
__global__ __launch_bounds__(512) void k_x3f(const float* __restrict__ h1,
                                             const float* __restrict__ hc,
                                             const float* __restrict__ sc1g,
                                             const float* __restrict__ sh1g,
                                             const ushort* __restrict__ W2b,
                                             const float* __restrict__ sc2g,
                                             const float* __restrict__ sh2g,
                                             const ushort* __restrict__ W3b,
                                             float* __restrict__ sum3,
                                             float* __restrict__ ssq3,
                                             float* __restrict__ Pmax,
                                             float* __restrict__ Pmin) {
  __shared__ __align__(16) ushort S1[256 * C_];    // 64 KB
  __shared__ __align__(16) ushort S2[128 * C2_];   // 64 KB (one half)
  __shared__ float h1s[4][C_], sc1[C_], sh1[C_];
  __shared__ float sc2s[C2_], sh2s[C2_];
  int nf0 = blockIdx.x * 4, b = nf0 >> 11;
  int t = threadIdx.x;
  if (t < C2_) { sc2s[t] = sc2g[t]; sh2s[t] = sh2g[t]; }
  build_S1_256(S1, h1, hc, sc1g, sh1g, nf0, b, h1s, sc1, sh1);
  int wv = t >> 6, lane = t & 63, lr = lane & 15, lg = lane >> 4;
  int RG = wv >> 2;            // row-group (128 tile rows each)
  int OB = (wv & 3) * 64;      // output-channel block
  int LB = RG * 64;            // this wave's S2 local row base

  float sm[4] = {0.f, 0.f, 0.f, 0.f}, sq[4] = {0.f, 0.f, 0.f, 0.f};
#pragma unroll 1
  for (int half = 0; half < 2; ++half) {
    // ---- stage 2: 64 rows -> S2 (write-through per mt; no big acc array)
    {
      s16x8 b2[4][4];
      const ushort* w2base = W2b + (OB + lr) * C_ + lg * 8;
#pragma unroll
      for (int ot = 0; ot < 4; ++ot)
#pragma unroll
        for (int ks = 0; ks < 4; ++ks)
          b2[ot][ks] = *(const s16x8*)(w2base + ot * 16 * C_ + ks * 32);
#pragma unroll
      for (int mt = 0; mt < 4; ++mt) {
        int gr = RG * 128 + half * 64 + mt * 16 + lr, rx = gr & 7;
        const ushort* s1r = S1 + gr * C_;
        s16x8 a[4];
#pragma unroll
        for (int ks = 0; ks < 4; ++ks)
          a[ks] = *(const s16x8*)(s1r + (((ks * 4 + lg) ^ rx) << 3));
#pragma unroll
        for (int ot = 0; ot < 4; ++ot) {
          f32x4 acc = {0.f, 0.f, 0.f, 0.f};
#pragma unroll
          for (int ks = 0; ks < 4; ++ks)
            acc = __builtin_amdgcn_mfma_f32_16x16x32_bf16(a[ks], b2[ot][ks], acc, 0, 0, 0);
          int o = OB + ot * 16 + lr;
          float sc = sc2s[o], sh = sh2s[o];
          int j2 = o >> 3, olow = o & 7;
#pragma unroll
          for (int r = 0; r < 4; ++r) {
            int ml = LB + mt * 16 + lg * 4 + r;
            S2[ml * C2_ + ((j2 ^ (ml & 7)) << 3) + olow] = f2b(lrelu(fmaf(sc, acc[r], sh)));
          }
        }
      }
    }
    __syncthreads();   // S2 half ready

    // ---- stage 3: X3 = S2 . W3^T ; stats + in-register pool over m
    {
      s16x8 b3[4][8];
      const ushort* w3base = W3b + (OB + lr) * C2_ + lg * 8;
#pragma unroll
      for (int ot = 0; ot < 4; ++ot)
#pragma unroll
        for (int ks = 0; ks < 8; ++ks)
          b3[ot][ks] = *(const s16x8*)(w3base + ot * 16 * C2_ + ks * 32);
      float pmx[4] = {-3.4e38f, -3.4e38f, -3.4e38f, -3.4e38f};
      float pmn[4] = { 3.4e38f,  3.4e38f,  3.4e38f,  3.4e38f};
#pragma unroll
      for (int mt = 0; mt < 4; ++mt) {
        int ml = LB + mt * 16 + lr, rx = ml & 7;
        const ushort* s2r = S2 + ml * C2_;
        s16x8 a[8];
#pragma unroll
        for (int ks = 0; ks < 8; ++ks)
          a[ks] = *(const s16x8*)(s2r + (((ks * 4 + lg) ^ rx) << 3));
#pragma unroll
        for (int ot = 0; ot < 4; ++ot) {
          f32x4 acc = {0.f, 0.f, 0.f, 0.f};
#pragma unroll
          for (int ks = 0; ks < 8; ++ks)
            acc = __builtin_amdgcn_mfma_f32_16x16x32_bf16(a[ks], b3[ot][ks], acc, 0, 0, 0);
#pragma unroll
          for (int r = 0; r < 4; ++r) {
            float v = acc[r];
            pmx[ot] = fmaxf(pmx[ot], v);
            pmn[ot] = fminf(pmn[ot], v);
            sm[ot] += v;
            sq[ot] = fmaf(v, v, sq[ot]);
          }
        }
      }
      int nf = nf0 + RG * 2 + half;
#pragma unroll
      for (int ot = 0; ot < 4; ++ot) {
        pmx[ot] = fmaxf(pmx[ot], __shfl_xor(pmx[ot], 16));
        pmx[ot] = fmaxf(pmx[ot], __shfl_xor(pmx[ot], 32));
        pmn[ot] = fminf(pmn[ot], __shfl_xor(pmn[ot], 16));
        pmn[ot] = fminf(pmn[ot], __shfl_xor(pmn[ot], 32));
        if (lg == 0) {
          int o = OB + ot * 16 + lr;
          Pmax[nf * C2_ + o] = pmx[ot];
          Pmin[nf * C2_ + o] = pmn[ot];
        }
      }
    }
    __syncthreads();   // stage3 reads done before next half overwrites S2
  }
#pragma unroll
  for (int ot = 0; ot < 4; ++ot) {
    sm[ot] += __shfl_xor(sm[ot], 16); sm[ot] += __shfl_xor(sm[ot], 32);
    sq[ot] += __shfl_xor(sq[ot], 16); sq[ot] += __shfl_xor(sq[ot], 32);
    if (lg == 0) {
      int o = OB + ot * 16 + lr;
      atomicAdd(&sum3[o], sm[ot]);
      atomicAdd(&ssq3[o], sq[ot]);
    }
  }
}

// ---------------- pool-select + fc1 (+stats4), 8 rows/block ----------------
__global__ __launch_bounds__(128) void k_fc1(const float* __restrict__ Pmax,
                                             const float* __restrict__ Pmin,
                                             const float* __restrict__ sc3,
                                             const float* __restrict__ sh3,
                                             const float* __restrict__ w1,
                                             const float* __restrict__ b1v,
                                             float* __restrict__ X4,
                                             float* __restrict__ sum4,
                                             float* __restrict__ ssq4) {
  __shared__ float pooled[8][C2_];
  __shared__ float sc3s[C2_], sh3s[C2_];
  int row0 = blockIdx.x * 8, t = threadIdx.x;
  sc3s[t] = sc3[t]; sc3s[t + 128] = sc3[t + 128];
  sh3s[t] = sh3[t]; sh3s[t + 128] = sh3[t + 128];
  __syncthreads();
  for (int idx = t; idx < 8 * C2_; idx += 128) {
    int r = idx >> 8, o = idx & 255;
    float sc = sc3s[o];
    float v = sc >= 0.f ? Pmax[(row0 + r) * C2_ + o] : Pmin[(row0 + r) * C2_ + o];
    pooled[r][o] = lrelu(fmaf(sc, v, sh3s[o]));
  }
  __syncthreads();
  const float* w = w1 + t * C2_;
  float bias = b1v[t];
  float acc[8] = {bias, bias, bias, bias, bias, bias, bias, bias};
  for (int c = 0; c < C2_; c += 4) {
    float4 wv = *(const float4*)(w + c);
#pragma unroll
    for (int r = 0; r < 8; ++r) {
      float4 pv = *(const float4*)(&pooled[r][c]);
      acc[r] = fmaf(wv.x, pv.x, fmaf(wv.y, pv.y, fmaf(wv.z, pv.z, fmaf(wv.w, pv.w, acc[r]))));
    }
  }
  float s = 0.f, s2 = 0.f;
#pragma unroll
  for (int r = 0; r < 8; ++r) {
    X4[(row0 + r) * H_ + t] = acc[r];
    s += acc[r]; s2 = fmaf(acc[r], acc[r], s2);
  }
  atomicAdd(&sum4[t], s);
  atomicAdd(&ssq4[t], s2);
}

// ---------------- bn4+relu + fc2 (+stats5), 8 rows/block ----------------
__global__ __launch_bounds__(64) void k_fc2(const float* __restrict__ X4,
                                            const float* __restrict__ sc4,
                                            const float* __restrict__ sh4,
                                            const float* __restrict__ w2,
                                            const float* __restrict__ b2v,
                                            float* __restrict__ X5,
                                            float* __restrict__ sum5,
                                            float* __restrict__ ssq5) {
  __shared__ float y[8][H_];
  int row0 = blockIdx.x * 8, t = threadIdx.x;
  for (int idx = t; idx < 8 * H_; idx += 64) {
    int r = idx >> 7, j = idx & 127;
    float x = fmaf(sc4[j], X4[(row0 + r) * H_ + j], sh4[j]);
    y[r][j] = x > 0.f ? x : 0.f;
  }
  __syncthreads();
  const float* w = w2 + t * H_;
  float bias = b2v[t];
  float acc[8] = {bias, bias, bias, bias, bias, bias, bias, bias};
  for (int c = 0; c < H_; c += 4) {
    float4 wv = *(const float4*)(w + c);
#pragma unroll
    for (int r = 0; r < 8; ++r) {
      float4 yv = *(const float4*)(&y[r][c]);
      acc[r] = fmaf(wv.x, yv.x, fmaf(wv.y, yv.y, fmaf(wv.z, yv.z, fmaf(wv.w, yv.w, acc[r]))));
    }
  }
  float s = 0.f, s2 = 0.f;
#pragma unroll
  for (int r = 0; r < 8; ++r) {
    X5[(row0 + r) * O_ + t] = acc[r];
    s += acc[r]; s2 = fmaf(acc[r], acc[r], s2);
  }
  atomicAdd(&sum5[t], s);
  atomicAdd(&ssq5[t], s2);
}

// ---------------- bn5 + relu -> out ----------------
__global__ __launch_bounds__(256) void k_out(const float* __restrict__ X5,
                                             const float* __restrict__ sc5,
                                             const float* __restrict__ sh5,
                                             float* __restrict__ out) {
  int i = blockIdx.x * 256 + threadIdx.x;
  float x = fmaf(sc5[i & (O_ - 1)], X5[i], sh5[i & (O_ - 1)]);
  out[i] = x > 0.f ? x : 0.f;
}

// ---------------- launch ----------------
extern "C" void kernel_launch(void* const* d_in, const int* in_sizes, int n_in,
                              void* d_out, int out_size, void* d_ws, size_t ws_size,
                              hipStream_t stream) {
  const float* pf   = (const float*)d_in[0];
  const float* cf   = (const float*)d_in[1];
  const float* W1   = (const float*)d_in[2];
  const float* g1   = (const float*)d_in[3];
  const float* b1   = (const float*)d_in[4];
  const float* W2   = (const float*)d_in[5];
  const float* g2   = (const float*)d_in[6];
  const float* b2   = (const float*)d_in[7];
  const float* W3   = (const float*)d_in[8];
  const float* g3   = (const float*)d_in[9];
  const float* b3   = (const float*)d_in[10];
  const float* fc1w = (const float*)d_in[11];
  const float* fc1b = (const float*)d_in[12];
  const float* g4   = (const float*)d_in[13];
  const float* b4   = (const float*)d_in[14];
  const float* fc2w = (const float*)d_in[15];
  const float* fc2b = (const float*)d_in[16];
  const float* g5   = (const float*)d_in[17];
  const float* b5   = (const float*)d_in[18];
  float* ws  = (float*)d_ws;
  float* out = (float*)d_out;
  ushort* w2b = (ushort*)(ws + WS_W2BF);
  ushort* w3b = (ushort*)(ws + WS_W3BF);

  hipMemsetAsync(ws + WS_ZERO_BEG, 0, WS_ZERO_CNT * sizeof(float), stream);

  k_cvtW<<<(C2_ * C2_) / 256, 256, 0, stream>>>(W2, W3, w2b, w3b);
  k_proj4<<<B_ * N_ / 4, 128, 0, stream>>>(pf, W1, ws + WS_H1, 0);
  k_proj4<<<B_ * M_ / 4, 128, 0, stream>>>(cf, W1, ws + WS_HC, C_);
  k_rowstats<<<(B_ * N_) / 32, 256, 0, stream>>>(ws + WS_H1, ws + WS_SUMA, ws + WS_SSQA, N_);
  k_rowstats<<<(B_ * M_) / 32, 256, 0, stream>>>(ws + WS_HC, ws + WS_SUMC, ws + WS_SSQC, M_);
  k_fin1<<<1, 128, 0, stream>>>(ws + WS_SUMA, ws + WS_SSQA, ws + WS_SUMC, ws + WS_SSQC,
                                g1, b1, ws + WS_SC1, ws + WS_SH1);
  k_x2f<<<B_ * N_ / 4, 512, 0, stream>>>(ws + WS_H1, ws + WS_HC, ws + WS_SC1, ws + WS_SH1,
                                         w2b, ws + WS_SUM2, ws + WS_SSQ2);
  k_finalize<<<1, C2_, 0, stream>>>(ws + WS_SUM2, ws + WS_SSQ2, g2, b2,
                                    ws + WS_SC2, ws + WS_SH2, C2_, 1.f / (B_ * N_ * M_));
  k_x3f<<<B_ * N_ / 4, 512, 0, stream>>>(ws + WS_H1, ws + WS_HC, ws + WS_SC1, ws + WS_SH1,
                                         w2b, ws + WS_SC2, ws + WS_SH2, w3b,
                                         ws + WS_SUM3, ws + WS_SSQ3,
                                         ws + WS_PMAX, ws + WS_PMIN);
  k_finalize<<<1, C2_, 0, stream>>>(ws + WS_SUM3, ws + WS_SSQ3, g3, b3,
                                    ws + WS_SC3, ws + WS_SH3, C2_, 1.f / (B_ * N_ * M_));
  k_fc1<<<B_ * N_ / 8, 128, 0, stream>>>(ws + WS_PMAX, ws + WS_PMIN, ws + WS_SC3, ws + WS_SH3,
                                         fc1w, fc1b, ws + WS_X4, ws + WS_SUM4, ws + WS_SSQ4);
  k_finalize<<<1, H_, 0, stream>>>(ws + WS_SUM4, ws + WS_SSQ4, g4, b4,
                                   ws + WS_SC4, ws + WS_SH4, H_, 1.f / (B_ * N_));
  k_fc2<<<B_ * N_ / 8, 64, 0, stream>>>(ws + WS_X4, ws + WS_SC4, ws + WS_SH4,
                                        fc2w, fc2b, ws + WS_X5, ws + WS_SUM5, ws + WS_SSQ5);
  k_finalize<<<1, O_, 0, stream>>>(ws + WS_SUM5, ws + WS_SSQ5, g5, b5,
                                   ws + WS_SC5, ws + WS_SH5, O_, 1.f / (B_ * N_));
  k_out<<<(B_ * N_ * O_) / 256, 256, 0, stream>>>(ws + WS_X5, ws + WS_SC5, ws + WS_SH5, out);
}

// Round 6
// 389.346 us; speedup vs baseline: 1.2142x; 1.2142x over previous
//
#include <hip/hip_runtime.h>
#include <math.h>

#define EPSV   1e-5f
#define SLOPE  0.2f

#define B_   2
#define N_   2048
#define M_   64
#define C_   128
#define C2_  256
#define H_   128
#define O_   64

typedef short  s16x8 __attribute__((ext_vector_type(8)));
typedef ushort u16x8 __attribute__((ext_vector_type(8)));
typedef float  f32x4 __attribute__((ext_vector_type(4)));

// ---------------- workspace (float offsets) ----------------
#define WS_H1      0            // [4096*128]
#define WS_HC      524288       // [128*128]
#define WS_PMAX    540672       // [4096*256]
#define WS_PMIN    1589248      // [4096*256]
#define WS_W2BF    2637824      // 256*128 bf16
#define WS_W3BF    2654208      // 256*256 bf16
#define WS_SUMA    2686976      // [2*128]
#define WS_SSQA    2687232
#define WS_SUMC    2687488
#define WS_SSQC    2687744
#define WS_SUM2    2688000      // [256]
#define WS_SSQ2    2688256
#define WS_SUM3    2688512
#define WS_SSQ3    2688768
#define WS_SUM4    2689024      // [128]
#define WS_SSQ4    2689152
#define WS_SUM5    2689280      // [64]
#define WS_SSQ5    2689344
#define WS_ZERO_BEG WS_SUMA
#define WS_ZERO_CNT (2689408 - WS_SUMA)
#define WS_SC1     2689408
#define WS_SH1     2689536
#define WS_SC2     2689664
#define WS_SH2     2689920
#define WS_SC3     2690176
#define WS_SH3     2690432
#define WS_SC4     2690688
#define WS_SH4     2690816
#define WS_SC5     2690944
#define WS_SH5     2691008
#define WS_X4      WS_H1        // reuse (H1 dead after k_x3f)
#define WS_X5      WS_PMIN      // reuse (PMIN dead after k_fc1)

__device__ inline ushort f2b(float x) {
  unsigned u = __builtin_bit_cast(unsigned, x);
  u += 0x7fffu + ((u >> 16) & 1u);
  return (ushort)(u >> 16);
}
__device__ inline float lrelu(float x) { return fmaxf(x, SLOPE * x); }

// ---------------- W -> bf16 ----------------
__global__ __launch_bounds__(256) void k_cvtW(const float* __restrict__ W2,
                                              const float* __restrict__ W3,
                                              ushort* __restrict__ w2b,
                                              ushort* __restrict__ w3b) {
  int i = blockIdx.x * 256 + threadIdx.x;
  if (i < C2_ * C_) w2b[i] = f2b(W2[i]);
  w3b[i] = f2b(W3[i]);
}

// ---------------- projections, 4 rows/block ----------------
__global__ __launch_bounds__(128) void k_proj4(const float* __restrict__ x,
                                               const float* __restrict__ W1,
                                               float* __restrict__ out, int col_off) {
  __shared__ float xs[4][C_];
  int row0 = blockIdx.x * 4, t = threadIdx.x;
#pragma unroll
  for (int r = 0; r < 4; ++r) xs[r][t] = x[(row0 + r) * C_ + t];
  __syncthreads();
  const float* w = W1 + t * (2 * C_) + col_off;
  float acc[4] = {0.f, 0.f, 0.f, 0.f};
  for (int c = 0; c < C_; c += 4) {
    float4 wv = *(const float4*)(w + c);
#pragma unroll
    for (int r = 0; r < 4; ++r) {
      float4 xv = *(const float4*)(&xs[r][c]);
      acc[r] = fmaf(wv.x, xv.x, fmaf(wv.y, xv.y, fmaf(wv.z, xv.z, fmaf(wv.w, xv.w, acc[r]))));
    }
  }
#pragma unroll
  for (int r = 0; r < 4; ++r) out[(row0 + r) * C_ + t] = acc[r];
}

// ---------------- coalesced per-(b,c) row stats ----------------
__global__ __launch_bounds__(256) void k_rowstats(const float* __restrict__ x,
                                                  float* __restrict__ sums,
                                                  float* __restrict__ ssqs,
                                                  int rows_per_b) {
  __shared__ float red[256];
  int t = threadIdx.x, c = t & 127, rr = t >> 7;
  int r0 = blockIdx.x * 32, b = r0 / rows_per_b;
  float s = 0.f, s2 = 0.f;
  for (int i = 0; i < 16; ++i) {
    float v = x[(r0 + rr + i * 2) * C_ + c];
    s += v; s2 = fmaf(v, v, s2);
  }
  red[t] = s;
  __syncthreads();
  if (t < 128) atomicAdd(&sums[b * C_ + t], red[t] + red[t + 128]);
  __syncthreads();
  red[t] = s2;
  __syncthreads();
  if (t < 128) atomicAdd(&ssqs[b * C_ + t], red[t] + red[t + 128]);
}

// ---------------- analytic BN1 params ----------------
__global__ __launch_bounds__(128) void k_fin1(const float* __restrict__ sumA,
                                              const float* __restrict__ ssqA,
                                              const float* __restrict__ sumC,
                                              const float* __restrict__ ssqC,
                                              const float* __restrict__ g,
                                              const float* __restrict__ bt,
                                              float* __restrict__ scale,
                                              float* __restrict__ shift) {
  int c = threadIdx.x;
  float sA0 = sumA[c], sA1 = sumA[C_ + c];
  float qA0 = ssqA[c], qA1 = ssqA[C_ + c];
  float sC0 = sumC[c], sC1 = sumC[C_ + c];
  float qC0 = ssqC[c], qC1 = ssqC[C_ + c];
  const float cnt = (float)B_ * N_ * M_;
  float mean = ((float)M_ * (sA0 + sA1) + (float)N_ * (sC0 + sC1)) / cnt;
  float ex2 = ((float)M_ * (qA0 + qA1) + (float)N_ * (qC0 + qC1)
               + 2.f * (sA0 * sC0 + sA1 * sC1)) / cnt;
  float var = ex2 - mean * mean;
  float sc = g[c] * rsqrtf(var + EPSV);
  scale[c] = sc;
  shift[c] = bt[c] - mean * sc;
}

// ---------------- finalize BN params from sums ----------------
__global__ void k_finalize(const float* __restrict__ sum, const float* __restrict__ ssq,
                           const float* __restrict__ g, const float* __restrict__ bt,
                           float* __restrict__ scale, float* __restrict__ shift,
                           int nch, float inv_cnt) {
  int o = threadIdx.x + blockIdx.x * blockDim.x;
  if (o < nch) {
    float mean = sum[o] * inv_cnt;
    float var = ssq[o] * inv_cnt - mean * mean;
    float sc = g[o] * rsqrtf(var + EPSV);
    scale[o] = sc;
    shift[o] = bt[o] - mean * sc;
  }
}

// ---------------- build S1 tile: 256 rows (4 n x 64 m), bf16 swizzled ----------------
// S1 ushort idx: r*128 + ((j ^ (r&7))<<3) + (c&7),  j = c>>3
__device__ inline void build_S1_256(ushort* S1, const float* __restrict__ h1,
                                    const float* __restrict__ hc,
                                    const float* __restrict__ sc1g,
                                    const float* __restrict__ sh1g,
                                    int nf0, int b,
                                    float (*h1s)[C_], float* sc1, float* sh1) {
  int t = threadIdx.x;
  h1s[t >> 7][t & 127] = h1[(nf0 + (t >> 7)) * C_ + (t & 127)];
  if (t < C_) { sc1[t] = sc1g[t]; sh1[t] = sh1g[t]; }
  __syncthreads();
  const float* hcb = hc + b * M_ * C_;
#pragma unroll
  for (int i = 0; i < 8; ++i) {
    int s = t + i * 512;
    int r = s >> 4, j = s & 15, c0 = j << 3;
    const float* hr = h1s[r >> 6];
    const float* src = hcb + (r & 63) * C_ + c0;
    float4 v0 = *(const float4*)(src);
    float4 v1 = *(const float4*)(src + 4);
    u16x8 q;
    q[0] = f2b(lrelu(fmaf(sc1[c0+0], hr[c0+0] + v0.x, sh1[c0+0])));
    q[1] = f2b(lrelu(fmaf(sc1[c0+1], hr[c0+1] + v0.y, sh1[c0+1])));
    q[2] = f2b(lrelu(fmaf(sc1[c0+2], hr[c0+2] + v0.z, sh1[c0+2])));
    q[3] = f2b(lrelu(fmaf(sc1[c0+3], hr[c0+3] + v0.w, sh1[c0+3])));
    q[4] = f2b(lrelu(fmaf(sc1[c0+4], hr[c0+4] + v1.x, sh1[c0+4])));
    q[5] = f2b(lrelu(fmaf(sc1[c0+5], hr[c0+5] + v1.y, sh1[c0+5])));
    q[6] = f2b(lrelu(fmaf(sc1[c0+6], hr[c0+6] + v1.z, sh1[c0+6])));
    q[7] = f2b(lrelu(fmaf(sc1[c0+7], hr[c0+7] + v1.w, sh1[c0+7])));
    *(u16x8*)(S1 + r * C_ + ((j ^ (r & 7)) << 3)) = q;
  }
  __syncthreads();
}

// ---------------- pass B: stats of X2 over a 256-row tile ----------------
__global__ __launch_bounds__(512, 2) void k_x2f(const float* __restrict__ h1,
                                                const float* __restrict__ hc,
                                                const float* __restrict__ sc1g,
                                                const float* __restrict__ sh1g,
                                                const ushort* __restrict__ W2b,
                                                float* __restrict__ sum2,
                                                float* __restrict__ ssq2) {
  __shared__ __align__(16) ushort S1[256 * C_];   // 64 KB
  __shared__ float h1s[4][C_], sc1[C_], sh1[C_];
  int nf0 = blockIdx.x * 4, b = nf0 >> 11;
  build_S1_256(S1, h1, hc, sc1g, sh1g, nf0, b, h1s, sc1, sh1);
  int t = threadIdx.x, wv = t >> 6, lane = t & 63, lr = lane & 15, lg = lane >> 4;
  int RB = (wv >> 2) * 128, OB = (wv & 3) * 64;

  s16x8 b2[4][4];
  const ushort* w2base = W2b + (OB + lr) * C_ + lg * 8;
#pragma unroll
  for (int ot = 0; ot < 4; ++ot)
#pragma unroll
    for (int ks = 0; ks < 4; ++ks)
      b2[ot][ks] = *(const s16x8*)(w2base + ot * 16 * C_ + ks * 32);

  float sm[4] = {0.f, 0.f, 0.f, 0.f}, sq[4] = {0.f, 0.f, 0.f, 0.f};
#pragma unroll
  for (int mt = 0; mt < 8; ++mt) {
    int rowm = RB + mt * 16 + lr, rx = rowm & 7;
    const ushort* s1r = S1 + rowm * C_;
    s16x8 a[4];
#pragma unroll
    for (int ks = 0; ks < 4; ++ks)
      a[ks] = *(const s16x8*)(s1r + (((ks * 4 + lg) ^ rx) << 3));
#pragma unroll
    for (int ot = 0; ot < 4; ++ot) {
      f32x4 acc = {0.f, 0.f, 0.f, 0.f};
#pragma unroll
      for (int ks = 0; ks < 4; ++ks)
        acc = __builtin_amdgcn_mfma_f32_16x16x32_bf16(a[ks], b2[ot][ks], acc, 0, 0, 0);
#pragma unroll
      for (int r = 0; r < 4; ++r) {
        sm[ot] += acc[r];
        sq[ot] = fmaf(acc[r], acc[r], sq[ot]);
      }
    }
  }
#pragma unroll
  for (int ot = 0; ot < 4; ++ot) {
    sm[ot] += __shfl_xor(sm[ot], 16); sm[ot] += __shfl_xor(sm[ot], 32);
    sq[ot] += __shfl_xor(sq[ot], 16); sq[ot] += __shfl_xor(sq[ot], 32);
    if (lg == 0) {
      int o = OB + ot * 16 + lr;
      atomicAdd(&sum2[o], sm[ot]);
      atomicAdd(&ssq2[o], sq[ot]);
    }
  }
}

// ---------------- pass C: stage2 + stage3 + pool, per-half, low-VGPR ----------------
// LDS: S1 (64 KB, live whole kernel) + S2 (64 KB, one 128-row half).
// S2 ushort idx: ml*256 + ((j ^ (ml&7))<<3) + (c&7), j = c>>3
// stage3: ot loop NOT unrolled; per-iter live regs ~100 (b3[8]=32, a[8]=32,
// acc 4, scalar pool/stats) -> fits the 128-VGPR budget, no spill.
__global__ __launch_bounds__(512, 2) void k_x3f(const float* __restrict__ h1,
                                                const float* __restrict__ hc,
                                                const float* __restrict__ sc1g,
                                                const float* __restrict__ sh1g,
                                                const ushort* __restrict__ W2b,
                                                const float* __restrict__ sc2g,
                                                const float* __restrict__ sh2g,
                                                const ushort* __restrict__ W3b,
                                                float* __restrict__ sum3,
                                                float* __restrict__ ssq3,
                                                float* __restrict__ Pmax,
                                                float* __restrict__ Pmin) {
  __shared__ __align__(16) ushort S1[256 * C_];    // 64 KB
  __shared__ __align__(16) ushort S2[128 * C2_];   // 64 KB (one half)
  __shared__ float h1s[4][C_], sc1[C_], sh1[C_];
  __shared__ float sc2s[C2_], sh2s[C2_];
  int nf0 = blockIdx.x * 4, b = nf0 >> 11;
  int t = threadIdx.x;
  if (t < C2_) { sc2s[t] = sc2g[t]; sh2s[t] = sh2g[t]; }
  build_S1_256(S1, h1, hc, sc1g, sh1g, nf0, b, h1s, sc1, sh1);
  int wv = t >> 6, lane = t & 63, lr = lane & 15, lg = lane >> 4;
  int RG = wv >> 2;            // row-group (2 x 128 tile rows)
  int OB = (wv & 3) * 64;      // output-channel block
  int LB = RG * 64;            // this wave's S2 local row base

#pragma unroll 1
  for (int half = 0; half < 2; ++half) {
    // ---- stage 2: 64 rows -> S2 (write-through per mt)
    {
      s16x8 b2[4][4];
      const ushort* w2base = W2b + (OB + lr) * C_ + lg * 8;
#pragma unroll
      for (int ot = 0; ot < 4; ++ot)
#pragma unroll
        for (int ks = 0; ks < 4; ++ks)
          b2[ot][ks] = *(const s16x8*)(w2base + ot * 16 * C_ + ks * 32);
#pragma unroll
      for (int mt = 0; mt < 4; ++mt) {
        int gr = RG * 128 + half * 64 + mt * 16 + lr, rx = gr & 7;
        const ushort* s1r = S1 + gr * C_;
        s16x8 a[4];
#pragma unroll
        for (int ks = 0; ks < 4; ++ks)
          a[ks] = *(const s16x8*)(s1r + (((ks * 4 + lg) ^ rx) << 3));
#pragma unroll
        for (int ot = 0; ot < 4; ++ot) {
          f32x4 acc = {0.f, 0.f, 0.f, 0.f};
#pragma unroll
          for (int ks = 0; ks < 4; ++ks)
            acc = __builtin_amdgcn_mfma_f32_16x16x32_bf16(a[ks], b2[ot][ks], acc, 0, 0, 0);
          int o = OB + ot * 16 + lr;
          float sc = sc2s[o], sh = sh2s[o];
          int j2 = o >> 3, olow = o & 7;
#pragma unroll
          for (int r = 0; r < 4; ++r) {
            int ml = LB + mt * 16 + lg * 4 + r;
            S2[ml * C2_ + ((j2 ^ (ml & 7)) << 3) + olow] = f2b(lrelu(fmaf(sc, acc[r], sh)));
          }
        }
      }
    }
    __syncthreads();   // S2 half ready

    // ---- stage 3: X3 = S2 . W3^T ; stats + in-register pool over m
    int nf = nf0 + RG * 2 + half;
#pragma unroll 1
    for (int ot = 0; ot < 4; ++ot) {
      int o = OB + ot * 16 + lr;
      s16x8 b3[8];
      const ushort* w3base = W3b + o * C2_ + lg * 8;
#pragma unroll
      for (int ks = 0; ks < 8; ++ks)
        b3[ks] = *(const s16x8*)(w3base + ks * 32);
      float pmx = -3.4e38f, pmn = 3.4e38f, sm = 0.f, sq = 0.f;
#pragma unroll
      for (int mt = 0; mt < 4; ++mt) {
        int ml = LB + mt * 16 + lr, rx = ml & 7;
        const ushort* s2r = S2 + ml * C2_;
        s16x8 a[8];
#pragma unroll
        for (int ks = 0; ks < 8; ++ks)
          a[ks] = *(const s16x8*)(s2r + (((ks * 4 + lg) ^ rx) << 3));
        f32x4 acc = {0.f, 0.f, 0.f, 0.f};
#pragma unroll
        for (int ks = 0; ks < 8; ++ks)
          acc = __builtin_amdgcn_mfma_f32_16x16x32_bf16(a[ks], b3[ks], acc, 0, 0, 0);
#pragma unroll
        for (int r = 0; r < 4; ++r) {
          float v = acc[r];
          pmx = fmaxf(pmx, v);
          pmn = fminf(pmn, v);
          sm += v;
          sq = fmaf(v, v, sq);
        }
      }
      pmx = fmaxf(pmx, __shfl_xor(pmx, 16)); pmx = fmaxf(pmx, __shfl_xor(pmx, 32));
      pmn = fminf(pmn, __shfl_xor(pmn, 16)); pmn = fminf(pmn, __shfl_xor(pmn, 32));
      sm += __shfl_xor(sm, 16); sm += __shfl_xor(sm, 32);
      sq += __shfl_xor(sq, 16); sq += __shfl_xor(sq, 32);
      if (lg == 0) {
        Pmax[nf * C2_ + o] = pmx;
        Pmin[nf * C2_ + o] = pmn;
        atomicAdd(&sum3[o], sm);
        atomicAdd(&ssq3[o], sq);
      }
    }
    __syncthreads();   // stage3 reads done before next half overwrites S2
  }
}

// ---------------- pool-select + fc1 (+stats4), 8 rows/block ----------------
__global__ __launch_bounds__(128) void k_fc1(const float* __restrict__ Pmax,
                                             const float* __restrict__ Pmin,
                                             const float* __restrict__ sc3,
                                             const float* __restrict__ sh3,
                                             const float* __restrict__ w1,
                                             const float* __restrict__ b1v,
                                             float* __restrict__ X4,
                                             float* __restrict__ sum4,
                                             float* __restrict__ ssq4) {
  __shared__ float pooled[8][C2_];
  __shared__ float sc3s[C2_], sh3s[C2_];
  int row0 = blockIdx.x * 8, t = threadIdx.x;
  sc3s[t] = sc3[t]; sc3s[t + 128] = sc3[t + 128];
  sh3s[t] = sh3[t]; sh3s[t + 128] = sh3[t + 128];
  __syncthreads();
  for (int idx = t; idx < 8 * C2_; idx += 128) {
    int r = idx >> 8, o = idx & 255;
    float sc = sc3s[o];
    float v = sc >= 0.f ? Pmax[(row0 + r) * C2_ + o] : Pmin[(row0 + r) * C2_ + o];
    pooled[r][o] = lrelu(fmaf(sc, v, sh3s[o]));
  }
  __syncthreads();
  const float* w = w1 + t * C2_;
  float bias = b1v[t];
  float acc[8] = {bias, bias, bias, bias, bias, bias, bias, bias};
  for (int c = 0; c < C2_; c += 4) {
    float4 wv = *(const float4*)(w + c);
#pragma unroll
    for (int r = 0; r < 8; ++r) {
      float4 pv = *(const float4*)(&pooled[r][c]);
      acc[r] = fmaf(wv.x, pv.x, fmaf(wv.y, pv.y, fmaf(wv.z, pv.z, fmaf(wv.w, pv.w, acc[r]))));
    }
  }
  float s = 0.f, s2 = 0.f;
#pragma unroll
  for (int r = 0; r < 8; ++r) {
    X4[(row0 + r) * H_ + t] = acc[r];
    s += acc[r]; s2 = fmaf(acc[r], acc[r], s2);
  }
  atomicAdd(&sum4[t], s);
  atomicAdd(&ssq4[t], s2);
}

// ---------------- bn4+relu + fc2 (+stats5), 8 rows/block ----------------
__global__ __launch_bounds__(64) void k_fc2(const float* __restrict__ X4,
                                            const float* __restrict__ sc4,
                                            const float* __restrict__ sh4,
                                            const float* __restrict__ w2,
                                            const float* __restrict__ b2v,
                                            float* __restrict__ X5,
                                            float* __restrict__ sum5,
                                            float* __restrict__ ssq5) {
  __shared__ float y[8][H_];
  int row0 = blockIdx.x * 8, t = threadIdx.x;
  for (int idx = t; idx < 8 * H_; idx += 64) {
    int r = idx >> 7, j = idx & 127;
    float x = fmaf(sc4[j], X4[(row0 + r) * H_ + j], sh4[j]);
    y[r][j] = x > 0.f ? x : 0.f;
  }
  __syncthreads();
  const float* w = w2 + t * H_;
  float bias = b2v[t];
  float acc[8] = {bias, bias, bias, bias, bias, bias, bias, bias};
  for (int c = 0; c < H_; c += 4) {
    float4 wv = *(const float4*)(w + c);
#pragma unroll
    for (int r = 0; r < 8; ++r) {
      float4 yv = *(const float4*)(&y[r][c]);
      acc[r] = fmaf(wv.x, yv.x, fmaf(wv.y, yv.y, fmaf(wv.z, yv.z, fmaf(wv.w, yv.w, acc[r]))));
    }
  }
  float s = 0.f, s2 = 0.f;
#pragma unroll
  for (int r = 0; r < 8; ++r) {
    X5[(row0 + r) * O_ + t] = acc[r];
    s += acc[r]; s2 = fmaf(acc[r], acc[r], s2);
  }
  atomicAdd(&sum5[t], s);
  atomicAdd(&ssq5[t], s2);
}

// ---------------- bn5 + relu -> out ----------------
__global__ __launch_bounds__(256) void k_out(const float* __restrict__ X5,
                                             const float* __restrict__ sc5,
                                             const float* __restrict__ sh5,
                                             float* __restrict__ out) {
  int i = blockIdx.x * 256 + threadIdx.x;
  float x = fmaf(sc5[i & (O_ - 1)], X5[i], sh5[i & (O_ - 1)]);
  out[i] = x > 0.f ? x : 0.f;
}

// ---------------- launch ----------------
extern "C" void kernel_launch(void* const* d_in, const int* in_sizes, int n_in,
                              void* d_out, int out_size, void* d_ws, size_t ws_size,
                              hipStream_t stream) {
  const float* pf   = (const float*)d_in[0];
  const float* cf   = (const float*)d_in[1];
  const float* W1   = (const float*)d_in[2];
  const float* g1   = (const float*)d_in[3];
  const float* b1   = (const float*)d_in[4];
  const float* W2   = (const float*)d_in[5];
  const float* g2   = (const float*)d_in[6];
  const float* b2   = (const float*)d_in[7];
  const float* W3   = (const float*)d_in[8];
  const float* g3   = (const float*)d_in[9];
  const float* b3   = (const float*)d_in[10];
  const float* fc1w = (const float*)d_in[11];
  const float* fc1b = (const float*)d_in[12];
  const float* g4   = (const float*)d_in[13];
  const float* b4   = (const float*)d_in[14];
  const float* fc2w = (const float*)d_in[15];
  const float* fc2b = (const float*)d_in[16];
  const float* g5   = (const float*)d_in[17];
  const float* b5   = (const float*)d_in[18];
  float* ws  = (float*)d_ws;
  float* out = (float*)d_out;
  ushort* w2b = (ushort*)(ws + WS_W2BF);
  ushort* w3b = (ushort*)(ws + WS_W3BF);

  hipMemsetAsync(ws + WS_ZERO_BEG, 0, WS_ZERO_CNT * sizeof(float), stream);

  k_cvtW<<<(C2_ * C2_) / 256, 256, 0, stream>>>(W2, W3, w2b, w3b);
  k_proj4<<<B_ * N_ / 4, 128, 0, stream>>>(pf, W1, ws + WS_H1, 0);
  k_proj4<<<B_ * M_ / 4, 128, 0, stream>>>(cf, W1, ws + WS_HC, C_);
  k_rowstats<<<(B_ * N_) / 32, 256, 0, stream>>>(ws + WS_H1, ws + WS_SUMA, ws + WS_SSQA, N_);
  k_rowstats<<<(B_ * M_) / 32, 256, 0, stream>>>(ws + WS_HC, ws + WS_SUMC, ws + WS_SSQC, M_);
  k_fin1<<<1, 128, 0, stream>>>(ws + WS_SUMA, ws + WS_SSQA, ws + WS_SUMC, ws + WS_SSQC,
                                g1, b1, ws + WS_SC1, ws + WS_SH1);
  k_x2f<<<B_ * N_ / 4, 512, 0, stream>>>(ws + WS_H1, ws + WS_HC, ws + WS_SC1, ws + WS_SH1,
                                         w2b, ws + WS_SUM2, ws + WS_SSQ2);
  k_finalize<<<1, C2_, 0, stream>>>(ws + WS_SUM2, ws + WS_SSQ2, g2, b2,
                                    ws + WS_SC2, ws + WS_SH2, C2_, 1.f / (B_ * N_ * M_));
  k_x3f<<<B_ * N_ / 4, 512, 0, stream>>>(ws + WS_H1, ws + WS_HC, ws + WS_SC1, ws + WS_SH1,
                                         w2b, ws + WS_SC2, ws + WS_SH2, w3b,
                                         ws + WS_SUM3, ws + WS_SSQ3,
                                         ws + WS_PMAX, ws + WS_PMIN);
  k_finalize<<<1, C2_, 0, stream>>>(ws + WS_SUM3, ws + WS_SSQ3, g3, b3,
                                    ws + WS_SC3, ws + WS_SH3, C2_, 1.f / (B_ * N_ * M_));
  k_fc1<<<B_ * N_ / 8, 128, 0, stream>>>(ws + WS_PMAX, ws + WS_PMIN, ws + WS_SC3, ws + WS_SH3,
                                         fc1w, fc1b, ws + WS_X4, ws + WS_SUM4, ws + WS_SSQ4);
  k_finalize<<<1, H_, 0, stream>>>(ws + WS_SUM4, ws + WS_SSQ4, g4, b4,
                                   ws + WS_SC4, ws + WS_SH4, H_, 1.f / (B_ * N_));
  k_fc2<<<B_ * N_ / 8, 64, 0, stream>>>(ws + WS_X4, ws + WS_SC4, ws + WS_SH4,
                                        fc2w, fc2b, ws + WS_X5, ws + WS_SUM5, ws + WS_SSQ5);
  k_finalize<<<1, O_, 0, stream>>>(ws + WS_SUM5, ws + WS_SSQ5, g5, b5,
                                   ws + WS_SC5, ws + WS_SH5, O_, 1.f / (B_ * N_));
  k_out<<<(B_ * N_ * O_) / 256, 256, 0, stream>>>(ws + WS_X5, ws + WS_SC5, ws + WS_SH5, out);
}

// Round 7
// 308.400 us; speedup vs baseline: 1.5329x; 1.2625x over previous
//
#include <hip/hip_runtime.h>
#include <math.h>

#define EPSV   1e-5f
#define SLOPE  0.2f

#define B_   2
#define N_   2048
#define M_   64
#define C_   128
#define C2_  256
#define H_   128
#define O_   64

typedef short  s16x8 __attribute__((ext_vector_type(8)));
typedef ushort u16x8 __attribute__((ext_vector_type(8)));
typedef float  f32x4 __attribute__((ext_vector_type(4)));

// ---------------- workspace (float offsets) ----------------
#define WS_H1      0            // [4096*128]
#define WS_HC      524288       // [128*128]
#define WS_PMAX    540672       // [4096*256]
#define WS_PMIN    1589248      // [4096*256]
#define WS_W2BF    2637824      // 256*128 bf16
#define WS_W3BF    2654208      // 256*256 bf16
#define WS_SUMA    2686976      // [2*128]
#define WS_SSQA    2687232
#define WS_SUMC    2687488
#define WS_SSQC    2687744
#define WS_SUM2    2688000      // [256]
#define WS_SSQ2    2688256
#define WS_SUM3    2688512
#define WS_SSQ3    2688768
#define WS_SUM4    2689024      // [128]
#define WS_SSQ4    2689152
#define WS_SUM5    2689280      // [64]
#define WS_SSQ5    2689344
#define WS_ZERO_BEG WS_SUMA
#define WS_ZERO_CNT (2689408 - WS_SUMA)
#define WS_SC1     2689408
#define WS_SH1     2689536
#define WS_SC2     2689664
#define WS_SH2     2689920
#define WS_SC3     2690176
#define WS_SH3     2690432
#define WS_SC4     2690688
#define WS_SH4     2690816
#define WS_SC5     2690944
#define WS_SH5     2691008
#define WS_X4      WS_H1        // reuse (H1 dead after k_x3f)
#define WS_X5      WS_PMIN      // reuse (PMIN dead after k_fc1)

__device__ inline ushort f2b(float x) {
  unsigned u = __builtin_bit_cast(unsigned, x);
  u += 0x7fffu + ((u >> 16) & 1u);
  return (ushort)(u >> 16);
}
__device__ inline float lrelu(float x) { return fmaxf(x, SLOPE * x); }

// ---------------- W -> bf16 ----------------
__global__ __launch_bounds__(256) void k_cvtW(const float* __restrict__ W2,
                                              const float* __restrict__ W3,
                                              ushort* __restrict__ w2b,
                                              ushort* __restrict__ w3b) {
  int i = blockIdx.x * 256 + threadIdx.x;
  if (i < C2_ * C_) w2b[i] = f2b(W2[i]);
  w3b[i] = f2b(W3[i]);
}

// ---------------- projections, 4 rows/block ----------------
__global__ __launch_bounds__(128) void k_proj4(const float* __restrict__ x,
                                               const float* __restrict__ W1,
                                               float* __restrict__ out, int col_off) {
  __shared__ float xs[4][C_];
  int row0 = blockIdx.x * 4, t = threadIdx.x;
#pragma unroll
  for (int r = 0; r < 4; ++r) xs[r][t] = x[(row0 + r) * C_ + t];
  __syncthreads();
  const float* w = W1 + t * (2 * C_) + col_off;
  float acc[4] = {0.f, 0.f, 0.f, 0.f};
  for (int c = 0; c < C_; c += 4) {
    float4 wv = *(const float4*)(w + c);
#pragma unroll
    for (int r = 0; r < 4; ++r) {
      float4 xv = *(const float4*)(&xs[r][c]);
      acc[r] = fmaf(wv.x, xv.x, fmaf(wv.y, xv.y, fmaf(wv.z, xv.z, fmaf(wv.w, xv.w, acc[r]))));
    }
  }
#pragma unroll
  for (int r = 0; r < 4; ++r) out[(row0 + r) * C_ + t] = acc[r];
}

// ---------------- coalesced per-(b,c) row stats ----------------
__global__ __launch_bounds__(256) void k_rowstats(const float* __restrict__ x,
                                                  float* __restrict__ sums,
                                                  float* __restrict__ ssqs,
                                                  int rows_per_b) {
  __shared__ float red[256];
  int t = threadIdx.x, c = t & 127, rr = t >> 7;
  int r0 = blockIdx.x * 32, b = r0 / rows_per_b;
  float s = 0.f, s2 = 0.f;
  for (int i = 0; i < 16; ++i) {
    float v = x[(r0 + rr + i * 2) * C_ + c];
    s += v; s2 = fmaf(v, v, s2);
  }
  red[t] = s;
  __syncthreads();
  if (t < 128) atomicAdd(&sums[b * C_ + t], red[t] + red[t + 128]);
  __syncthreads();
  red[t] = s2;
  __syncthreads();
  if (t < 128) atomicAdd(&ssqs[b * C_ + t], red[t] + red[t + 128]);
}

// ---------------- analytic BN1 params ----------------
__global__ __launch_bounds__(128) void k_fin1(const float* __restrict__ sumA,
                                              const float* __restrict__ ssqA,
                                              const float* __restrict__ sumC,
                                              const float* __restrict__ ssqC,
                                              const float* __restrict__ g,
                                              const float* __restrict__ bt,
                                              float* __restrict__ scale,
                                              float* __restrict__ shift) {
  int c = threadIdx.x;
  float sA0 = sumA[c], sA1 = sumA[C_ + c];
  float qA0 = ssqA[c], qA1 = ssqA[C_ + c];
  float sC0 = sumC[c], sC1 = sumC[C_ + c];
  float qC0 = ssqC[c], qC1 = ssqC[C_ + c];
  const float cnt = (float)B_ * N_ * M_;
  float mean = ((float)M_ * (sA0 + sA1) + (float)N_ * (sC0 + sC1)) / cnt;
  float ex2 = ((float)M_ * (qA0 + qA1) + (float)N_ * (qC0 + qC1)
               + 2.f * (sA0 * sC0 + sA1 * sC1)) / cnt;
  float var = ex2 - mean * mean;
  float sc = g[c] * rsqrtf(var + EPSV);
  scale[c] = sc;
  shift[c] = bt[c] - mean * sc;
}

// ---------------- finalize BN params from sums ----------------
__global__ void k_finalize(const float* __restrict__ sum, const float* __restrict__ ssq,
                           const float* __restrict__ g, const float* __restrict__ bt,
                           float* __restrict__ scale, float* __restrict__ shift,
                           int nch, float inv_cnt) {
  int o = threadIdx.x + blockIdx.x * blockDim.x;
  if (o < nch) {
    float mean = sum[o] * inv_cnt;
    float var = ssq[o] * inv_cnt - mean * mean;
    float sc = g[o] * rsqrtf(var + EPSV);
    scale[o] = sc;
    shift[o] = bt[o] - mean * sc;
  }
}

// ---------------- build S1 tile: 256 rows (4 n x 64 m), bf16 swizzled ----------------
// S1 ushort idx: r*128 + ((j ^ (r&7))<<3) + (c&7),  j = c>>3
__device__ inline void build_S1_256(ushort* S1, const float* __restrict__ h1,
                                    const float* __restrict__ hc,
                                    const float* __restrict__ sc1g,
                                    const float* __restrict__ sh1g,
                                    int nf0, int b,
                                    float (*h1s)[C_], float* sc1, float* sh1) {
  int t = threadIdx.x;
  h1s[t >> 7][t & 127] = h1[(nf0 + (t >> 7)) * C_ + (t & 127)];
  if (t < C_) { sc1[t] = sc1g[t]; sh1[t] = sh1g[t]; }
  __syncthreads();
  const float* hcb = hc + b * M_ * C_;
#pragma unroll
  for (int i = 0; i < 8; ++i) {
    int s = t + i * 512;
    int r = s >> 4, j = s & 15, c0 = j << 3;
    const float* hr = h1s[r >> 6];
    const float* src = hcb + (r & 63) * C_ + c0;
    float4 v0 = *(const float4*)(src);
    float4 v1 = *(const float4*)(src + 4);
    u16x8 q;
    q[0] = f2b(lrelu(fmaf(sc1[c0+0], hr[c0+0] + v0.x, sh1[c0+0])));
    q[1] = f2b(lrelu(fmaf(sc1[c0+1], hr[c0+1] + v0.y, sh1[c0+1])));
    q[2] = f2b(lrelu(fmaf(sc1[c0+2], hr[c0+2] + v0.z, sh1[c0+2])));
    q[3] = f2b(lrelu(fmaf(sc1[c0+3], hr[c0+3] + v0.w, sh1[c0+3])));
    q[4] = f2b(lrelu(fmaf(sc1[c0+4], hr[c0+4] + v1.x, sh1[c0+4])));
    q[5] = f2b(lrelu(fmaf(sc1[c0+5], hr[c0+5] + v1.y, sh1[c0+5])));
    q[6] = f2b(lrelu(fmaf(sc1[c0+6], hr[c0+6] + v1.z, sh1[c0+6])));
    q[7] = f2b(lrelu(fmaf(sc1[c0+7], hr[c0+7] + v1.w, sh1[c0+7])));
    *(u16x8*)(S1 + r * C_ + ((j ^ (r & 7)) << 3)) = q;
  }
  __syncthreads();
}

// ---------------- pass B: stats of X2 over a 256-row tile (low-VGPR) ----------------
// ot loop NOT unrolled: per-iter live ~55 regs (b2[4]=16, a[4]=16) -> no spill.
__global__ __launch_bounds__(512, 2) void k_x2f(const float* __restrict__ h1,
                                                const float* __restrict__ hc,
                                                const float* __restrict__ sc1g,
                                                const float* __restrict__ sh1g,
                                                const ushort* __restrict__ W2b,
                                                float* __restrict__ sum2,
                                                float* __restrict__ ssq2) {
  __shared__ __align__(16) ushort S1[256 * C_];   // 64 KB
  __shared__ float h1s[4][C_], sc1[C_], sh1[C_];
  int nf0 = blockIdx.x * 4, b = nf0 >> 11;
  build_S1_256(S1, h1, hc, sc1g, sh1g, nf0, b, h1s, sc1, sh1);
  int t = threadIdx.x, wv = t >> 6, lane = t & 63, lr = lane & 15, lg = lane >> 4;
  int RB = (wv >> 2) * 128, OB = (wv & 3) * 64;

#pragma unroll 1
  for (int ot = 0; ot < 4; ++ot) {
    int o = OB + ot * 16 + lr;
    s16x8 b2[4];
    const ushort* w2base = W2b + o * C_ + lg * 8;
#pragma unroll
    for (int ks = 0; ks < 4; ++ks)
      b2[ks] = *(const s16x8*)(w2base + ks * 32);
    float sm = 0.f, sq = 0.f;
#pragma unroll
    for (int mt = 0; mt < 8; ++mt) {
      int rowm = RB + mt * 16 + lr, rx = rowm & 7;
      const ushort* s1r = S1 + rowm * C_;
      s16x8 a[4];
#pragma unroll
      for (int ks = 0; ks < 4; ++ks)
        a[ks] = *(const s16x8*)(s1r + (((ks * 4 + lg) ^ rx) << 3));
      f32x4 acc = {0.f, 0.f, 0.f, 0.f};
#pragma unroll
      for (int ks = 0; ks < 4; ++ks)
        acc = __builtin_amdgcn_mfma_f32_16x16x32_bf16(a[ks], b2[ks], acc, 0, 0, 0);
#pragma unroll
      for (int r = 0; r < 4; ++r) {
        sm += acc[r];
        sq = fmaf(acc[r], acc[r], sq);
      }
    }
    sm += __shfl_xor(sm, 16); sm += __shfl_xor(sm, 32);
    sq += __shfl_xor(sq, 16); sq += __shfl_xor(sq, 32);
    if (lg == 0) {
      atomicAdd(&sum2[o], sm);
      atomicAdd(&ssq2[o], sq);
    }
  }
}

// ---------------- pass C: stage2 + stage3 + pool, per-half, low-VGPR ----------------
// LDS: S1 (64 KB, live whole kernel) + S2 (64 KB, one 128-row half).
// S2 ushort idx: ml*256 + ((j ^ (ml&7))<<3) + (c&7), j = c>>3
// BOTH stage loops keep ot outer with unroll 1: peak live ~60 (stage2) / ~85
// (stage3) regs -> fits 128-VGPR budget with no spill (R6 spilled b2[4][4]).
__global__ __launch_bounds__(512, 2) void k_x3f(const float* __restrict__ h1,
                                                const float* __restrict__ hc,
                                                const float* __restrict__ sc1g,
                                                const float* __restrict__ sh1g,
                                                const ushort* __restrict__ W2b,
                                                const float* __restrict__ sc2g,
                                                const float* __restrict__ sh2g,
                                                const ushort* __restrict__ W3b,
                                                float* __restrict__ sum3,
                                                float* __restrict__ ssq3,
                                                float* __restrict__ Pmax,
                                                float* __restrict__ Pmin) {
  __shared__ __align__(16) ushort S1[256 * C_];    // 64 KB
  __shared__ __align__(16) ushort S2[128 * C2_];   // 64 KB (one half)
  __shared__ float h1s[4][C_], sc1[C_], sh1[C_];
  __shared__ float sc2s[C2_], sh2s[C2_];
  int nf0 = blockIdx.x * 4, b = nf0 >> 11;
  int t = threadIdx.x;
  if (t < C2_) { sc2s[t] = sc2g[t]; sh2s[t] = sh2g[t]; }
  build_S1_256(S1, h1, hc, sc1g, sh1g, nf0, b, h1s, sc1, sh1);
  int wv = t >> 6, lane = t & 63, lr = lane & 15, lg = lane >> 4;
  int RG = wv >> 2;            // row-group (2 x 128 tile rows)
  int OB = (wv & 3) * 64;      // output-channel block
  int LB = RG * 64;            // this wave's S2 local row base

#pragma unroll 1
  for (int half = 0; half < 2; ++half) {
    // ---- stage 2: 64 rows -> S2 (ot outer, b2[4] only)
#pragma unroll 1
    for (int ot = 0; ot < 4; ++ot) {
      int o = OB + ot * 16 + lr;
      s16x8 b2[4];
      const ushort* w2base = W2b + o * C_ + lg * 8;
#pragma unroll
      for (int ks = 0; ks < 4; ++ks)
        b2[ks] = *(const s16x8*)(w2base + ks * 32);
      float sc = sc2s[o], sh = sh2s[o];
      int j2 = o >> 3, olow = o & 7;
#pragma unroll
      for (int mt = 0; mt < 4; ++mt) {
        int gr = RG * 128 + half * 64 + mt * 16 + lr, rx = gr & 7;
        const ushort* s1r = S1 + gr * C_;
        s16x8 a[4];
#pragma unroll
        for (int ks = 0; ks < 4; ++ks)
          a[ks] = *(const s16x8*)(s1r + (((ks * 4 + lg) ^ rx) << 3));
        f32x4 acc = {0.f, 0.f, 0.f, 0.f};
#pragma unroll
        for (int ks = 0; ks < 4; ++ks)
          acc = __builtin_amdgcn_mfma_f32_16x16x32_bf16(a[ks], b2[ks], acc, 0, 0, 0);
#pragma unroll
        for (int r = 0; r < 4; ++r) {
          int ml = LB + mt * 16 + lg * 4 + r;
          S2[ml * C2_ + ((j2 ^ (ml & 7)) << 3) + olow] = f2b(lrelu(fmaf(sc, acc[r], sh)));
        }
      }
    }
    __syncthreads();   // S2 half ready

    // ---- stage 3: X3 = S2 . W3^T ; stats + in-register pool over m
    int nf = nf0 + RG * 2 + half;
#pragma unroll 1
    for (int ot = 0; ot < 4; ++ot) {
      int o = OB + ot * 16 + lr;
      s16x8 b3[8];
      const ushort* w3base = W3b + o * C2_ + lg * 8;
#pragma unroll
      for (int ks = 0; ks < 8; ++ks)
        b3[ks] = *(const s16x8*)(w3base + ks * 32);
      float pmx = -3.4e38f, pmn = 3.4e38f, sm = 0.f, sq = 0.f;
#pragma unroll
      for (int mt = 0; mt < 4; ++mt) {
        int ml = LB + mt * 16 + lr, rx = ml & 7;
        const ushort* s2r = S2 + ml * C2_;
        s16x8 a[8];
#pragma unroll
        for (int ks = 0; ks < 8; ++ks)
          a[ks] = *(const s16x8*)(s2r + (((ks * 4 + lg) ^ rx) << 3));
        f32x4 acc = {0.f, 0.f, 0.f, 0.f};
#pragma unroll
        for (int ks = 0; ks < 8; ++ks)
          acc = __builtin_amdgcn_mfma_f32_16x16x32_bf16(a[ks], b3[ks], acc, 0, 0, 0);
#pragma unroll
        for (int r = 0; r < 4; ++r) {
          float v = acc[r];
          pmx = fmaxf(pmx, v);
          pmn = fminf(pmn, v);
          sm += v;
          sq = fmaf(v, v, sq);
        }
      }
      pmx = fmaxf(pmx, __shfl_xor(pmx, 16)); pmx = fmaxf(pmx, __shfl_xor(pmx, 32));
      pmn = fminf(pmn, __shfl_xor(pmn, 16)); pmn = fminf(pmn, __shfl_xor(pmn, 32));
      sm += __shfl_xor(sm, 16); sm += __shfl_xor(sm, 32);
      sq += __shfl_xor(sq, 16); sq += __shfl_xor(sq, 32);
      if (lg == 0) {
        Pmax[nf * C2_ + o] = pmx;
        Pmin[nf * C2_ + o] = pmn;
        atomicAdd(&sum3[o], sm);
        atomicAdd(&ssq3[o], sq);
      }
    }
    __syncthreads();   // stage3 reads done before next half overwrites S2
  }
}

// ---------------- pool-select + fc1 (+stats4), 8 rows/block ----------------
__global__ __launch_bounds__(128) void k_fc1(const float* __restrict__ Pmax,
                                             const float* __restrict__ Pmin,
                                             const float* __restrict__ sc3,
                                             const float* __restrict__ sh3,
                                             const float* __restrict__ w1,
                                             const float* __restrict__ b1v,
                                             float* __restrict__ X4,
                                             float* __restrict__ sum4,
                                             float* __restrict__ ssq4) {
  __shared__ float pooled[8][C2_];
  __shared__ float sc3s[C2_], sh3s[C2_];
  int row0 = blockIdx.x * 8, t = threadIdx.x;
  sc3s[t] = sc3[t]; sc3s[t + 128] = sc3[t + 128];
  sh3s[t] = sh3[t]; sh3s[t + 128] = sh3[t + 128];
  __syncthreads();
  for (int idx = t; idx < 8 * C2_; idx += 128) {
    int r = idx >> 8, o = idx & 255;
    float sc = sc3s[o];
    float v = sc >= 0.f ? Pmax[(row0 + r) * C2_ + o] : Pmin[(row0 + r) * C2_ + o];
    pooled[r][o] = lrelu(fmaf(sc, v, sh3s[o]));
  }
  __syncthreads();
  const float* w = w1 + t * C2_;
  float bias = b1v[t];
  float acc[8] = {bias, bias, bias, bias, bias, bias, bias, bias};
  for (int c = 0; c < C2_; c += 4) {
    float4 wv = *(const float4*)(w + c);
#pragma unroll
    for (int r = 0; r < 8; ++r) {
      float4 pv = *(const float4*)(&pooled[r][c]);
      acc[r] = fmaf(wv.x, pv.x, fmaf(wv.y, pv.y, fmaf(wv.z, pv.z, fmaf(wv.w, pv.w, acc[r]))));
    }
  }
  float s = 0.f, s2 = 0.f;
#pragma unroll
  for (int r = 0; r < 8; ++r) {
    X4[(row0 + r) * H_ + t] = acc[r];
    s += acc[r]; s2 = fmaf(acc[r], acc[r], s2);
  }
  atomicAdd(&sum4[t], s);
  atomicAdd(&ssq4[t], s2);
}

// ---------------- bn4+relu + fc2 (+stats5), 8 rows/block ----------------
__global__ __launch_bounds__(64) void k_fc2(const float* __restrict__ X4,
                                            const float* __restrict__ sc4,
                                            const float* __restrict__ sh4,
                                            const float* __restrict__ w2,
                                            const float* __restrict__ b2v,
                                            float* __restrict__ X5,
                                            float* __restrict__ sum5,
                                            float* __restrict__ ssq5) {
  __shared__ float y[8][H_];
  int row0 = blockIdx.x * 8, t = threadIdx.x;
  for (int idx = t; idx < 8 * H_; idx += 64) {
    int r = idx >> 7, j = idx & 127;
    float x = fmaf(sc4[j], X4[(row0 + r) * H_ + j], sh4[j]);
    y[r][j] = x > 0.f ? x : 0.f;
  }
  __syncthreads();
  const float* w = w2 + t * H_;
  float bias = b2v[t];
  float acc[8] = {bias, bias, bias, bias, bias, bias, bias, bias};
  for (int c = 0; c < H_; c += 4) {
    float4 wv = *(const float4*)(w + c);
#pragma unroll
    for (int r = 0; r < 8; ++r) {
      float4 yv = *(const float4*)(&y[r][c]);
      acc[r] = fmaf(wv.x, yv.x, fmaf(wv.y, yv.y, fmaf(wv.z, yv.z, fmaf(wv.w, yv.w, acc[r]))));
    }
  }
  float s = 0.f, s2 = 0.f;
#pragma unroll
  for (int r = 0; r < 8; ++r) {
    X5[(row0 + r) * O_ + t] = acc[r];
    s += acc[r]; s2 = fmaf(acc[r], acc[r], s2);
  }
  atomicAdd(&sum5[t], s);
  atomicAdd(&ssq5[t], s2);
}

// ---------------- bn5 + relu -> out ----------------
__global__ __launch_bounds__(256) void k_out(const float* __restrict__ X5,
                                             const float* __restrict__ sc5,
                                             const float* __restrict__ sh5,
                                             float* __restrict__ out) {
  int i = blockIdx.x * 256 + threadIdx.x;
  float x = fmaf(sc5[i & (O_ - 1)], X5[i], sh5[i & (O_ - 1)]);
  out[i] = x > 0.f ? x : 0.f;
}

// ---------------- launch ----------------
extern "C" void kernel_launch(void* const* d_in, const int* in_sizes, int n_in,
                              void* d_out, int out_size, void* d_ws, size_t ws_size,
                              hipStream_t stream) {
  const float* pf   = (const float*)d_in[0];
  const float* cf   = (const float*)d_in[1];
  const float* W1   = (const float*)d_in[2];
  const float* g1   = (const float*)d_in[3];
  const float* b1   = (const float*)d_in[4];
  const float* W2   = (const float*)d_in[5];
  const float* g2   = (const float*)d_in[6];
  const float* b2   = (const float*)d_in[7];
  const float* W3   = (const float*)d_in[8];
  const float* g3   = (const float*)d_in[9];
  const float* b3   = (const float*)d_in[10];
  const float* fc1w = (const float*)d_in[11];
  const float* fc1b = (const float*)d_in[12];
  const float* g4   = (const float*)d_in[13];
  const float* b4   = (const float*)d_in[14];
  const float* fc2w = (const float*)d_in[15];
  const float* fc2b = (const float*)d_in[16];
  const float* g5   = (const float*)d_in[17];
  const float* b5   = (const float*)d_in[18];
  float* ws  = (float*)d_ws;
  float* out = (float*)d_out;
  ushort* w2b = (ushort*)(ws + WS_W2BF);
  ushort* w3b = (ushort*)(ws + WS_W3BF);

  hipMemsetAsync(ws + WS_ZERO_BEG, 0, WS_ZERO_CNT * sizeof(float), stream);

  k_cvtW<<<(C2_ * C2_) / 256, 256, 0, stream>>>(W2, W3, w2b, w3b);
  k_proj4<<<B_ * N_ / 4, 128, 0, stream>>>(pf, W1, ws + WS_H1, 0);
  k_proj4<<<B_ * M_ / 4, 128, 0, stream>>>(cf, W1, ws + WS_HC, C_);
  k_rowstats<<<(B_ * N_) / 32, 256, 0, stream>>>(ws + WS_H1, ws + WS_SUMA, ws + WS_SSQA, N_);
  k_rowstats<<<(B_ * M_) / 32, 256, 0, stream>>>(ws + WS_HC, ws + WS_SUMC, ws + WS_SSQC, M_);
  k_fin1<<<1, 128, 0, stream>>>(ws + WS_SUMA, ws + WS_SSQA, ws + WS_SUMC, ws + WS_SSQC,
                                g1, b1, ws + WS_SC1, ws + WS_SH1);
  k_x2f<<<B_ * N_ / 4, 512, 0, stream>>>(ws + WS_H1, ws + WS_HC, ws + WS_SC1, ws + WS_SH1,
                                         w2b, ws + WS_SUM2, ws + WS_SSQ2);
  k_finalize<<<1, C2_, 0, stream>>>(ws + WS_SUM2, ws + WS_SSQ2, g2, b2,
                                    ws + WS_SC2, ws + WS_SH2, C2_, 1.f / (B_ * N_ * M_));
  k_x3f<<<B_ * N_ / 4, 512, 0, stream>>>(ws + WS_H1, ws + WS_HC, ws + WS_SC1, ws + WS_SH1,
                                         w2b, ws + WS_SC2, ws + WS_SH2, w3b,
                                         ws + WS_SUM3, ws + WS_SSQ3,
                                         ws + WS_PMAX, ws + WS_PMIN);
  k_finalize<<<1, C2_, 0, stream>>>(ws + WS_SUM3, ws + WS_SSQ3, g3, b3,
                                    ws + WS_SC3, ws + WS_SH3, C2_, 1.f / (B_ * N_ * M_));
  k_fc1<<<B_ * N_ / 8, 128, 0, stream>>>(ws + WS_PMAX, ws + WS_PMIN, ws + WS_SC3, ws + WS_SH3,
                                         fc1w, fc1b, ws + WS_X4, ws + WS_SUM4, ws + WS_SSQ4);
  k_finalize<<<1, H_, 0, stream>>>(ws + WS_SUM4, ws + WS_SSQ4, g4, b4,
                                   ws + WS_SC4, ws + WS_SH4, H_, 1.f / (B_ * N_));
  k_fc2<<<B_ * N_ / 8, 64, 0, stream>>>(ws + WS_X4, ws + WS_SC4, ws + WS_SH4,
                                        fc2w, fc2b, ws + WS_X5, ws + WS_SUM5, ws + WS_SSQ5);
  k_finalize<<<1, O_, 0, stream>>>(ws + WS_SUM5, ws + WS_SSQ5, g5, b5,
                                   ws + WS_SC5, ws + WS_SH5, O_, 1.f / (B_ * N_));
  k_out<<<(B_ * N_ * O_) / 256, 256, 0, stream>>>(ws + WS_X5, ws + WS_SC5, ws + WS_SH5, out);
}